// Round 13
// baseline (235.842 us; speedup 1.0000x reference)
//
#include <hip/hip_runtime.h>
#include <hip/hip_bf16.h>
#include <math.h>

#define DEV __device__ __forceinline__

constexpr int BATCH = 4096;
constexpr int NBA = 512;    // pool blocks, 8 img each (ka also carries 16 hist blocks)
constexpr int NBB = 2048;   // conv1-stats blocks (2 img each)
constexpr int NBC = 4096;   // fused conv blocks (1 img each), launched as 2x2048 (r13 probe)
constexpr int NBE = 256;    // fc1 blocks (16 img each, 512 threads, all 128 cols)
constexpr int NBW = 16;     // hist slices

// workspace layout (float offsets)
constexpr size_t OFF_POOLED = 0;                            // 4096*196
constexpr size_t OFF_Y2P = OFF_POOLED + (size_t)BATCH*196;  // 4096*400
constexpr size_t OFF_ST1 = OFF_Y2P;                         // 64*2048*4; consumed by kstat1 BEFORE kc writes Y2P
constexpr size_t OFF_H3  = OFF_Y2P + (size_t)BATCH*400;     // 4096*128
constexpr size_t OFF_ST2 = OFF_H3;                          // 16*4096*4; consumed by kstat2 BEFORE ke writes H3
constexpr size_t OFF_W2  = OFF_H3 + (size_t)BATCH*128;      // W2F u16[9][2][2][4][16][8] lane-linear
constexpr size_t OFF_W3  = OFF_W2 + 9216;                   // W3F u16: [kt25][ct8][lane64][8] hi/lo K-interleaved (51200 f32 exactly)
constexpr size_t OFF_W4  = OFF_W3 + 51200;                  // 1280 [oc*128+k]
constexpr size_t OFF_WSC = OFF_W4 + 1280;                   // 4 layer scales
constexpr size_t OFF_BN1 = OFF_WSC + 4;                     // 64*4
constexpr size_t OFF_BN2 = OFF_BN1 + 256;                   // 16*4
constexpr size_t OFF_GMM = OFF_BN2 + 64;                    // 8 encoded slots
constexpr size_t OFF_ONS = OFF_GMM + 8;                     // 16 per-slice sum(hw_one)
constexpr size_t OFF_T   = OFF_ONS + 16;                    // (unused)
constexpr size_t OFF_MMA = OFF_T + 4;                       // 512*2 pooled min/max partials; REUSED by ke for fc1 min/max partials
constexpr size_t OFF_HIST= OFF_MMA + 1024;                  // 16*2048 per-slice pass-1 histograms
constexpr size_t OFF_W1M = OFF_HIST + 32768;                // W1F u16[4][2][4][16][8] (2048 floats)
constexpr size_t OFF_SEL = OFF_W1M + 2048;                  // 8 uints: per-L {b0, r1}
constexpr size_t OFF_H2G = OFF_SEL + 8;                     // 4*1024 uints pass-2 global hists
constexpr size_t OFF_H3G = OFF_H2G + 4096;                  // 4*1024 uints pass-3 global hists
// GMM: [0]=pooled min [1]=pooled max [2]=bn1 tmin [3]=bn1 tmax [4]=bn2 tmin [5]=bn2 tmax [6,7]=unused
// NOTE (r5): cooperative grid.sync() on MI355X cost ~17us/sync at 16 blocks -- tiny launches are CHEAPER.
// NOTE (r7): kc 2-img/block -> VGPR 52->96 -> occupancy 34->19% -> +11us. Occupancy > L1 reuse here.
// NOTE (r9/r12): kc flat ~45.5us across 4 structural variants -> per-block critical-path floor; parked.
// NOTE (r13): kc split into 2x2048 PROBE -- drops kc rows to ~23us so top-5 reveals hidden #2 kernel.

typedef __attribute__((ext_vector_type(8))) short bf16x8;
typedef __attribute__((ext_vector_type(4))) float f32x4;

struct InPtrs {
  const float* x;
  const float* sc[4];
  const float* sg[4];
  const float* on[4];
  const float* ze[4];
  const int* qb;
};

// hist-slice partition: 16 slices over 4 layers
__constant__ const int KW_L[16]  ={0,1,1,2,2,2,2,2,2,2,2,2,2,2,2,3};
__constant__ const int KW_S[16]  ={0,0,1,0,1,2,3,4,5,6,7,8,9,10,11,0};
__constant__ const int KW_NB[4]  ={1,2,12,1};
__constant__ const int KW_N[4]   ={576,9216,51200,1280};
__constant__ const int KW_FAN[4] ={9,576,400,128};
__constant__ const int KW_BW0[4] ={0,1,3,15};
__constant__ const int KW_BW1[4] ={1,3,15,16};

DEV unsigned fenc(float f){ unsigned u=__float_as_uint(f); return (u&0x80000000u)? ~u : (u|0x80000000u); }
DEV float fdec(unsigned e){ return __uint_as_float((e&0x80000000u)? (e&0x7fffffffu) : ~e); }
DEV unsigned short f2bf(float f){ unsigned u=__float_as_uint(f); return (unsigned short)((u + 0x7fffu + ((u>>16)&1u))>>16); }

DEV float blk_sum(float v, float* red, int t){
  red[t]=v; __syncthreads();
  for (int s=128;s>0;s>>=1){ if(t<s) red[t]+=red[t+s]; __syncthreads(); }
  float r=red[0]; __syncthreads();
  return r;
}
DEV float blk_min(float v, float* red, int t){
  red[t]=v; __syncthreads();
  for (int s=128;s>0;s>>=1){ if(t<s) red[t]=fminf(red[t],red[t+s]); __syncthreads(); }
  float r=red[0]; __syncthreads();
  return r;
}
DEV float blk_max(float v, float* red, int t){
  red[t]=v; __syncthreads();
  for (int s=128;s>0;s>>=1){ if(t<s) red[t]=fmaxf(red[t],red[t+s]); __syncthreads(); }
  float r=red[0]; __syncthreads();
  return r;
}

// find bucket from top with 256 threads; nbins in {1024,2048}; returns {bucket, remainder}
DEV int2 find256(const int* hist, int nbins, int kk, int t, int* suf, int* sh2){
  const int G=nbins>>8;
  const int lo=t*G;
  int g=0;
  for (int b=0;b<G;++b) g+=hist[lo+b];
  suf[t]=g; __syncthreads();
  for (int s=1;s<256;s<<=1){
    int add=(t+s<256)?suf[t+s]:0;
    __syncthreads();
    suf[t]+=add;
    __syncthreads();
  }
  const int S=suf[t];
  const int Snext=(t<255)?suf[t+1]:0;
  if (S>=kk && Snext<kk){
    int c2=Snext;
    for (int b=lo+G-1;b>=lo;--b){
      c2+=hist[b];
      if (c2>=kk){ sh2[0]=b; sh2[1]=kk-(c2-hist[b]); break; }
    }
  }
  __syncthreads();
  int2 r=make_int2(sh2[0],sh2[1]);
  __syncthreads();
  return r;
}

// conv1 patch matrix, quad-planar CONFLICT-FREE layout: PATQ[quad][pos][8 u16].
// Planes 2,3 (k16..31) must be zeroed by caller; plane1 word0 carries e8 (k9..15 zero).
DEV void build_patq(unsigned* PATQ, const unsigned short* qxs, int t){
  for (int pos=t; pos<144; pos+=256){
    int py=(pos*171)>>11;          // pos/12 for pos<144
    int px=pos-py*12;
    const unsigned short* q0=qxs+py*16+px;
    unsigned e0=q0[0],  e1=q0[1],  e2=q0[2];
    unsigned e3=q0[16], e4=q0[17], e5=q0[18];
    unsigned e6=q0[32], e7=q0[33], e8=q0[34];
    *(uint4*)(PATQ+pos*4)      =make_uint4(e0|(e1<<16), e2|(e3<<16), e4|(e5<<16), e6|(e7<<16));
    *(uint4*)(PATQ+(144+pos)*4)=make_uint4(e8, 0u, 0u, 0u);
  }
}

// ---------------- KA: blocks<512: maxpool (8 img/block, div-free) + min/max partials
//                    (block0 also zeroes pass2/3 hists). blocks 512..527: per-slice pass-1 hist + sum(hw_one).
__global__ __launch_bounds__(256) void ka_kernel(InPtrs in, float* __restrict__ ws){
  const int t=threadIdx.x, blk=blockIdx.x;
  __shared__ int h[2048];
  __shared__ float red[256];
  if (blk<NBA){
    if (blk==0){
      unsigned* Z=(unsigned*)(ws+OFF_H2G);
      for (int i=t;i<8192;i+=256) Z[i]=0u;
    }
    const float* x=in.x;
    float* pooled=ws+OFF_POOLED;
    float lmn=3.4e38f, lmx=-3.4e38f;
    if (t<196){
      const int oy=(t*2341)>>15;       // t/14, exact for t<196
      const int ox=t-oy*14;
      const float* xb=x+(size_t)blk*8*784+oy*56+ox*2;
      #pragma unroll
      for (int im=0; im<8; ++im){
        const float* px=xb+im*784;
        float m=fmaxf(fmaxf(px[0],px[1]),fmaxf(px[28],px[29]));
        pooled[(size_t)(blk*8+im)*196+t]=m;
        lmn=fminf(lmn,m); lmx=fmaxf(lmx,m);
      }
    }
    float bmn=blk_min(lmn,red,t);
    float bmx=blk_max(lmx,red,t);
    if (t==0){ ws[OFF_MMA+blk*2]=bmn; ws[OFF_MMA+blk*2+1]=bmx; }
  } else {
    const int bw=blk-NBA;
    const int L=KW_L[bw], s=KW_S[bw], nb=KW_NB[L];
    const int n4=KW_N[L]>>2;
    const int lo=(int)(((long long)n4*s)/nb), hi=(int)(((long long)n4*(s+1))/nb);
    const float4* sc4=(const float4*)in.sc[L];
    const float4* on4=(const float4*)in.on[L];
    for (int i=t;i<2048;i+=256) h[i]=0;
    __syncthreads();
    float onsum=0.f;
    for (int i=lo+t;i<hi;i+=256){
      float4 v=sc4[i];
      atomicAdd(&h[(__float_as_uint(v.x)&0x7fffffffu)>>20],1);
      atomicAdd(&h[(__float_as_uint(v.y)&0x7fffffffu)>>20],1);
      atomicAdd(&h[(__float_as_uint(v.z)&0x7fffffffu)>>20],1);
      atomicAdd(&h[(__float_as_uint(v.w)&0x7fffffffu)>>20],1);
      float4 o=on4[i];
      onsum+=(o.x+o.y)+(o.z+o.w);
    }
    __syncthreads();
    unsigned* GH=(unsigned*)(ws+OFF_HIST);
    for (int i=t;i<2048;i+=256) GH[bw*2048+i]=(unsigned)h[i];
    float S=blk_sum(onsum,red,t);
    if (t==0) ws[OFF_ONS+bw]=S;
  }
}

// ---------------- KWP2: (absorbed kw2a) per-block: merge pass-1 hists + find (b0,r1) for own L;
// block0: pooled reduce + GMM init; block15: W1F zero; then pass-2 conditional histogram ----------------
__global__ __launch_bounds__(256) void kwp2_kernel(InPtrs in, float* __restrict__ ws){
  const int t=threadIdx.x, bw=blockIdx.x;
  __shared__ int hist[2048];
  __shared__ int suf[256];
  __shared__ int sh2[2];
  __shared__ float redm[256], redx[256];
  const int L=KW_L[bw], s=KW_S[bw], nb=KW_NB[L];
  const int n4=KW_N[L]>>2;
  const int lo=(int)(((long long)n4*s)/nb), hi=(int)(((long long)n4*(s+1))/nb);
  if (bw==0){
    float a0=ws[OFF_MMA+2*t],       a1=ws[OFF_MMA+2*(t+256)];
    float b0v=ws[OFF_MMA+2*t+1],    b1v=ws[OFF_MMA+2*(t+256)+1];
    redm[t]=fminf(a0,a1); redx[t]=fmaxf(b0v,b1v);
    __syncthreads();
    for (int st=128;st>0;st>>=1){
      if (t<st){ redm[t]=fminf(redm[t],redm[t+st]); redx[t]=fmaxf(redx[t],redx[t+st]); }
      __syncthreads();
    }
    unsigned* U=(unsigned*)(ws+OFF_GMM);
    if (t==0){ U[0]=fenc(redm[0]); U[1]=fenc(redx[0]); }
    if (t>=2 && t<8) U[t]=(t&1)? 0u : 0xFFFFFFFFu;
    __syncthreads();
  }
  if (bw==15){
    unsigned* z=(unsigned*)(ws+OFF_W1M);     // zero W1F (k>=9 pads); consumed by kw3 (2 launches later)
    for (int i=t;i<2048;i+=256) z[i]=0u;
  }
  // merged pass-1 hist for this block's L + find1 (each block recomputes -- cheap, removes a launch)
  const unsigned* GH=(const unsigned*)(ws+OFF_HIST);
  for (int i=t;i<2048;i+=256){
    int sm=0;
    for (int b2=KW_BW0[L]; b2<KW_BW1[L]; ++b2) sm+=(int)GH[b2*2048+i];
    hist[i]=sm;
  }
  __syncthreads();
  int2 f1=find256(hist,2048,KW_N[L]>>1,t,suf,sh2);
  const unsigned b0=(unsigned)f1.x;
  if (s==0 && t==0){
    unsigned* SEL=(unsigned*)(ws+OFF_SEL);
    SEL[L*2]=(unsigned)f1.x; SEL[L*2+1]=(unsigned)f1.y;
  }
  // pass-2 hist (bits [19:10])
  const float4* sc4=(const float4*)in.sc[L];
  unsigned* GH2=(unsigned*)(ws+OFF_H2G)+L*1024;
  for (int i=lo+t;i<hi;i+=256){
    float4 v=sc4[i];
    unsigned ux=__float_as_uint(v.x)&0x7fffffffu;
    unsigned uy=__float_as_uint(v.y)&0x7fffffffu;
    unsigned uz=__float_as_uint(v.z)&0x7fffffffu;
    unsigned uw=__float_as_uint(v.w)&0x7fffffffu;
    if ((ux>>20)==b0) atomicAdd(&GH2[(ux>>10)&1023u],1u);
    if ((uy>>20)==b0) atomicAdd(&GH2[(uy>>10)&1023u],1u);
    if ((uz>>20)==b0) atomicAdd(&GH2[(uz>>10)&1023u],1u);
    if ((uw>>20)==b0) atomicAdd(&GH2[(uw>>10)&1023u],1u);
  }
}

// ---------------- KWP3: per-block find (b1,r2) over hist2, then pass-3 conditional histogram ----------------
__global__ __launch_bounds__(256) void kwp3_kernel(InPtrs in, float* __restrict__ ws){
  const int t=threadIdx.x, bw=blockIdx.x;
  const int L=KW_L[bw], s=KW_S[bw], nb=KW_NB[L];
  const int n4=KW_N[L]>>2;
  const int lo=(int)(((long long)n4*s)/nb), hi=(int)(((long long)n4*(s+1))/nb);
  const unsigned* SEL=(const unsigned*)(ws+OFF_SEL);
  const unsigned b0=SEL[L*2]; const int r1=(int)SEL[L*2+1];
  __shared__ int hist[1024];
  __shared__ int suf[256];
  __shared__ int sh2[2];
  const unsigned* GH2=(const unsigned*)(ws+OFF_H2G)+L*1024;
  for (int i=t;i<1024;i+=256) hist[i]=(int)GH2[i];
  __syncthreads();
  int2 f2=find256(hist,1024,r1,t,suf,sh2);
  const unsigned pre=(b0<<10)|(unsigned)f2.x;
  const float4* sc4=(const float4*)in.sc[L];
  unsigned* GH3=(unsigned*)(ws+OFF_H3G)+L*1024;
  for (int i=lo+t;i<hi;i+=256){
    float4 v=sc4[i];
    unsigned ux=__float_as_uint(v.x)&0x7fffffffu;
    unsigned uy=__float_as_uint(v.y)&0x7fffffffu;
    unsigned uz=__float_as_uint(v.z)&0x7fffffffu;
    unsigned uw=__float_as_uint(v.w)&0x7fffffffu;
    if ((ux>>10)==pre) atomicAdd(&GH3[ux&1023u],1u);
    if ((uy>>10)==pre) atomicAdd(&GH3[uy&1023u],1u);
    if ((uz>>10)==pre) atomicAdd(&GH3[uz&1023u],1u);
    if ((uw>>10)==pre) atomicAdd(&GH3[uw&1023u],1u);
  }
}

// ---------------- KW3: per-block finds -> exact T; slice-parallel weight writes ----------------
__global__ __launch_bounds__(256) void kw3_kernel(InPtrs in, float* __restrict__ ws){
  const int t=threadIdx.x, bw=blockIdx.x;
  const int L=KW_L[bw], s=KW_S[bw], nb=KW_NB[L];
  const int n4=KW_N[L]>>2;
  const int lo=(int)(((long long)n4*s)/nb), hi=(int)(((long long)n4*(s+1))/nb);
  const unsigned* SEL=(const unsigned*)(ws+OFF_SEL);
  const unsigned b0=SEL[L*2]; const int r1=(int)SEL[L*2+1];
  __shared__ int hist[1024];
  __shared__ int suf[256];
  __shared__ int sh2[2];
  const unsigned* GH2=(const unsigned*)(ws+OFF_H2G)+L*1024;
  for (int i=t;i<1024;i+=256) hist[i]=(int)GH2[i];
  __syncthreads();
  int2 f2=find256(hist,1024,r1,t,suf,sh2);
  const unsigned pre=(b0<<10)|(unsigned)f2.x;
  const int r2=f2.y;
  __syncthreads();
  const unsigned* GH3=(const unsigned*)(ws+OFF_H3G)+L*1024;
  for (int i=t;i<1024;i+=256) hist[i]=(int)GH3[i];
  __syncthreads();
  int2 f3=find256(hist,1024,r2,t,suf,sh2);
  const unsigned T=(pre<<10)|(unsigned)f3.x;
  if (s==0 && t==0){
    float os=0.f;
    for (int b=KW_BW0[L]; b<KW_BW1[L]; ++b) os+=ws[OFF_ONS+b];
    ws[OFF_WSC+L]=(os/(float)KW_N[L])*sqrtf((float)KW_FAN[L])*0.5f;
  }
  const float4* sc4=(const float4*)in.sc[L];
  const float4* sg4=(const float4*)in.sg[L];
  const float4* on4=(const float4*)in.on[L];
  const float4* ze4=(const float4*)in.ze[L];
  float* wout=ws+OFF_W4;
  unsigned* W3Fu=(unsigned*)(ws+OFF_W3);               // fc1 MFMA layout, hi/lo K-interleaved
  unsigned short* W1F=(unsigned short*)(ws+OFF_W1M);   // [ocT][h][quad][oc16][8]
  unsigned short* W2F=(unsigned short*)(ws+OFF_W2);    // [kykx][s][h][quad][oc16][8]
  for (int i4=lo+t;i4<hi;i4+=256){
    float4 sv4=sc4[i4], g=sg4[i4], o=on4[i4], z=ze4[i4];
    float sv[4]={sv4.x,sv4.y,sv4.z,sv4.w}, gv[4]={g.x,g.y,g.z,g.w};
    float ov[4]={o.x,o.y,o.z,o.w}, zv[4]={z.x,z.y,z.z,z.w};
    #pragma unroll
    for (int j=0;j<4;++j){
      int i=i4*4+j;
      unsigned u=__float_as_uint(sv[j])&0x7fffffffu;
      float w=gv[j]*((u>=T)? ov[j] : zv[j]);
      if (L==0){
        int oc=i/9; int k=i-oc*9;
        int ocT=oc>>4, ocL=oc&15, quad=k>>3, kj=k&7;
        unsigned short hb=f2bf(w);
        float lo2=w-__uint_as_float((unsigned)hb<<16);
        W1F[((((ocT*2+0)*4+quad)*16+ocL)<<3)+kj]=hb;
        W1F[((((ocT*2+1)*4+quad)*16+ocL)<<3)+kj]=f2bf(lo2);
      } else if (L==1){
        int oc=i/576; int r=i-oc*576; int ic=r/9; int kp=r-ic*9;
        int ss=ic>>5, rem=ic&31, quad=rem>>3, kj=rem&7;
        unsigned short hb=f2bf(w);
        float lo2=w-__uint_as_float((unsigned)hb<<16);
        W2F[(((((kp*2+ss)*2+0)*4+quad)*16+oc)<<3)+kj]=hb;
        W2F[(((((kp*2+ss)*2+1)*4+quad)*16+oc)<<3)+kj]=f2bf(lo2);
      } else if (L==2){
        // fc1 weight: oc in [0,128), kk in [0,400). k_eff = 2*kk (+1 for lo half).
        int oc=i/400; int kk=i-oc*400;
        unsigned short hb=f2bf(w);
        float lo2=w-__uint_as_float((unsigned)hb<<16);
        unsigned short lb=f2bf(lo2);
        int ct=oc>>4, l15=oc&15;
        unsigned idx=((unsigned)((kk>>4)*8+ct)*64u + (unsigned)(((kk>>2)&3)*16+l15))*4u + (unsigned)(kk&3);
        W3Fu[idx]=(unsigned)hb | ((unsigned)lb<<16);
      } else {
        wout[i]=w;
      }
    }
  }
}

// ---------------- KB: conv1 via MFMA -> per-channel BN1 stats partials (2 img/block) ----------------
__global__ __launch_bounds__(256) void kb_kernel(InPtrs in, const float* __restrict__ wsr, float* __restrict__ wsw){
  const int t=threadIdx.x, blk=blockIdx.x;
  __shared__ unsigned short qxs[256];
  __shared__ __align__(16) unsigned PAT[2304];   // PATQ[quad][pos144][4 dw]
  __shared__ float xw[1024];
  const float* pooled=wsr+OFF_POOLED;
  const unsigned* U=(const unsigned*)(wsr+OFF_GMM);
  const float mn0=fdec(U[0]);
  const float mx0=fdec(U[1]);
  const float lvf=(float)((1<<in.qb[0])-1);
  const float s0=(mx0-mn0)/lvf, inv_s0=1.0f/s0, zp0=floorf(mn0/s0);
  const float sv=s0/wsr[OFF_WSC+0];
  const int w=t>>6, lane=t&63, l15=lane&15, quad=lane>>4;
  const unsigned short* W1F=(const unsigned short*)(wsr+OFF_W1M);
  bf16x8 bh[4], bl[4];
  #pragma unroll
  for (int ocT=0; ocT<4; ++ocT){
    bh[ocT]=*(const bf16x8*)(W1F+(((ocT*2+0)*64+lane)<<3));
    bl[ocT]=*(const bf16x8*)(W1F+(((ocT*2+1)*64+lane)<<3));
  }
  for (int i=1152+t; i<2304; i+=256) PAT[i]=0u;   // zero planes 2,3 once (k16..31)
  float sum[4], sq[4], mn[4], mx[4];
  #pragma unroll
  for (int i=0;i<4;++i){ sum[i]=0.f; sq[i]=0.f; mn[i]=3.4e38f; mx[i]=-3.4e38f; }
  #pragma unroll
  for (int img=0; img<2; ++img){
    if (t<224){
      int row=t>>4, col=t&15;
      float q=0.f;
      if (col<14){ float xx=pooled[(size_t)(blk*2+img)*196+row*14+col]; q=rintf((xx-mn0)*inv_s0)+zp0; }
      qxs[t]=(unsigned short)(__float_as_uint(q)>>16);
    }
    __syncthreads();
    build_patq(PAT,qxs,t);
    __syncthreads();
    const unsigned short* PATu=(const unsigned short*)PAT;
    #pragma unroll
    for (int ocT=0; ocT<4; ++ocT){
      for (int tl=w; tl<9; tl+=4){
        bf16x8 a=*(const bf16x8*)(PATu+((quad*144+tl*16+l15)<<3));
        f32x4 acc=(f32x4){0.f,0.f,0.f,0.f};
        acc=__builtin_amdgcn_mfma_f32_16x16x32_bf16(a,bh[ocT],acc,0,0,0);
        acc=__builtin_amdgcn_mfma_f32_16x16x32_bf16(a,bl[ocT],acc,0,0,0);
        #pragma unroll
        for (int r=0;r<4;++r){
          float v=acc[r];
          sum[ocT]+=v; sq[ocT]=fmaf(v,v,sq[ocT]);
          mn[ocT]=fminf(mn[ocT],v); mx[ocT]=fmaxf(mx[ocT],v);
        }
      }
    }
    __syncthreads();   // conv1 reads of PAT done before next img's quant/PAT overwrite
  }
  #pragma unroll
  for (int ocT=0; ocT<4; ++ocT){
    float s=sum[ocT], q2=sq[ocT], a=mn[ocT], b=mx[ocT];
    #pragma unroll
    for (int d=16;d<64;d<<=1){
      s+=__shfl_xor(s,d);
      q2+=__shfl_xor(q2,d);
      a=fminf(a,__shfl_xor(a,d));
      b=fmaxf(b,__shfl_xor(b,d));
    }
    if (quad==0){
      float* p=xw+((w*4+ocT)*16+l15)*4;
      p[0]=s; p[1]=q2; p[2]=a; p[3]=b;
    }
  }
  __syncthreads();
  if (t<64){
    float s=0.f,q2=0.f,a=3.4e38f,b=-3.4e38f;
    #pragma unroll
    for (int w2=0;w2<4;++w2){
      const float* p=xw+((w2*4+(t>>4))*16+(t&15))*4;
      s+=p[0]; q2+=p[1]; a=fminf(a,p[2]); b=fmaxf(b,p[3]);
    }
    float* p=wsw+OFF_ST1+((size_t)t*NBB+blk)*4;
    p[0]=s*sv; p[1]=q2*sv*sv; p[2]=a*sv; p[3]=b*sv;
  }
}

// ---------------- kstat ----------------
__global__ __launch_bounds__(256) void kstat_kernel(const float* __restrict__ wsr, float* __restrict__ wsw,
                                                    unsigned long long inoff, int nparts, float Nf,
                                                    unsigned long long outoff, int mmslot){
  const int c=blockIdx.x, t=threadIdx.x;
  __shared__ float red[256];
  const float* p=wsr+inoff+(size_t)c*nparts*4;
  float sum=0.f,sq=0.f,mn=3.4e38f,mx=-3.4e38f;
  for (int i=t;i<nparts;i+=256){
    sum+=p[i*4]; sq+=p[i*4+1];
    mn=fminf(mn,p[i*4+2]); mx=fmaxf(mx,p[i*4+3]);
  }
  float S=blk_sum(sum,red,t);
  float Q=blk_sum(sq,red,t);
  float MN=blk_min(mn,red,t);
  float MX=blk_max(mx,red,t);
  if (t==0){
    float mean=S/Nf;
    float var=fmaxf(Q/Nf-mean*mean,0.f);
    float sd=sqrtf(var+1e-5f);
    float* o=wsw+outoff+c*4;
    float tmn=(MN-mean)/sd, tmx=(MX-mean)/sd;
    o[0]=mean; o[1]=sd; o[2]=tmn; o[3]=tmx;
    unsigned* U=(unsigned*)(wsw+OFF_GMM);
    atomicMin(&U[mmslot],fenc(tmn));
    atomicMax(&U[mmslot+1],fenc(tmx));
  }
}

// ---------------- KC: conv1(MFMA)->bn1/relu/quant->conv2(MFMA)->pool, 1 img/block, blk0-offset ----------------
__global__ __launch_bounds__(256) void kc_kernel(InPtrs in, const float* __restrict__ wsr, float* __restrict__ wsw, int blk0){
  const int t=threadIdx.x, blk=blockIdx.x+blk0;
  __shared__ unsigned short qxs[256];
  __shared__ __align__(16) unsigned PATBUF[2304];        // PATQ (2304 dw) aliased by c2s[16][100] (1600 dw)
  __shared__ __align__(16) unsigned short actA[144*72];  // [cell][72: 64 ch + 8 pad] bf16 codes, 144B rows
  __shared__ float sA2[64], sB2[64];
  unsigned* PAT=PATBUF;
  float (*c2s)[100]=(float(*)[100])PATBUF;
  const float* pooled=wsr+OFF_POOLED;
  const unsigned* U=(const unsigned*)(wsr+OFF_GMM);
  const float mn0=fdec(U[0]);
  const float mx0=fdec(U[1]);
  const float rmn=fdec(U[2]);
  const float rmx=fdec(U[3]);
  const float lvf=(float)((1<<in.qb[0])-1);
  const float s0=(mx0-mn0)/lvf, inv_s0=1.0f/s0, zp0=floorf(mn0/s0);
  const float s1w=wsr[OFF_WSC+0], s2w=wsr[OFF_WSC+1];
  const float s2=(fmaxf(rmx,0.f)-fmaxf(rmn,0.f))/lvf;
  const float inv_s2=1.0f/s2;
  const float g2=s2/s2w;
  if (t<64){
    float m=wsr[OFF_BN1+t*4], sd=wsr[OFF_BN1+t*4+1];
    sA2[t]=s0/(s1w*sd)*inv_s2;
    sB2[t]=(-m/sd)*inv_s2;
  }
  if (t<224){
    int row=t>>4, col=t&15;
    float q=0.f;
    if (col<14){ float xx=pooled[(size_t)blk*196+row*14+col]; q=rintf((xx-mn0)*inv_s0)+zp0; }
    qxs[t]=(unsigned short)(__float_as_uint(q)>>16);
  }
  for (int i=1152+t; i<2304; i+=256) PAT[i]=0u;   // zero PATQ planes 2,3
  __syncthreads();
  build_patq(PAT,qxs,t);
  __syncthreads();
  const int w=t>>6, lane=t&63;
  const int l15=lane&15, quad=lane>>4;
  // conv1 MFMA (swapped) + bn/relu/quant -> actA via packed b64
  {
    const unsigned short* W1F=(const unsigned short*)(wsr+OFF_W1M);
    const unsigned short* PATu=(const unsigned short*)PAT;
    #pragma unroll
    for (int ocT=0; ocT<4; ++ocT){
      bf16x8 bh=*(const bf16x8*)(W1F+(((ocT*2+0)*64+lane)<<3));
      bf16x8 bl=*(const bf16x8*)(W1F+(((ocT*2+1)*64+lane)<<3));
      const int oc0=ocT*16+quad*4;
      const float a20=sA2[oc0],   b20=sB2[oc0];
      const float a21=sA2[oc0+1], b21=sB2[oc0+1];
      const float a22=sA2[oc0+2], b22=sB2[oc0+2];
      const float a23=sA2[oc0+3], b23=sB2[oc0+3];
      for (int tl=w; tl<9; tl+=4){
        bf16x8 a=*(const bf16x8*)(PATu+((quad*144+tl*16+l15)<<3));
        f32x4 acc=(f32x4){0.f,0.f,0.f,0.f};
        acc=__builtin_amdgcn_mfma_f32_16x16x32_bf16(bh,a,acc,0,0,0);
        acc=__builtin_amdgcn_mfma_f32_16x16x32_bf16(bl,a,acc,0,0,0);
        const int pos=tl*16+l15;
        float f0=fminf(rintf(fmaxf(fmaf(acc[0],a20,b20),0.f)),lvf);
        float f1=fminf(rintf(fmaxf(fmaf(acc[1],a21,b21),0.f)),lvf);
        float f2v=fminf(rintf(fmaxf(fmaf(acc[2],a22,b22),0.f)),lvf);
        float f3=fminf(rintf(fmaxf(fmaf(acc[3],a23,b23),0.f)),lvf);
        unsigned w0=(__float_as_uint(f0)>>16)|((__float_as_uint(f1)>>16)<<16);
        unsigned w1=(__float_as_uint(f2v)>>16)|((__float_as_uint(f3)>>16)<<16);
        *(uint2*)(actA+pos*72+oc0)=make_uint2(w0,w1);
      }
    }
  }
  __syncthreads();
  // conv2 via MFMA: 7 M-tiles of 16 positions; wave w owns taus {w, w+4}
  {
    const int nT=(w<3)?2:1;
    const unsigned short* W2F=(const unsigned short*)(wsr+OFF_W2);
    int abase[2];
    #pragma unroll
    for (int i=0;i<2;++i){
      int tau=w+i*4;
      int posb=tau*16+l15;
      int pc=posb>99?99:posb;
      int py=pc/10, px=pc-py*10;
      abase[i]=(py*12+px)*144+quad*16;   // BYTE offset in actA
    }
    f32x4 acc[2];
    acc[0]=(f32x4){0.f,0.f,0.f,0.f};
    acc[1]=(f32x4){0.f,0.f,0.f,0.f};
    const char* actB=(const char*)actA;
    #pragma unroll 3
    for (int kykx=0;kykx<9;++kykx){
      int ky=(kykx*11)>>5;           // kykx/3 for kykx<9
      int kx=kykx-ky*3;
      int co=(ky*12+kx)*144;
      #pragma unroll
      for (int s=0;s<2;++s){
        bf16x8 bh=*(const bf16x8*)(W2F+((((kykx*2+s)*2+0)*64+lane)<<3));
        bf16x8 bl=*(const bf16x8*)(W2F+((((kykx*2+s)*2+1)*64+lane)<<3));
        #pragma unroll
        for (int i=0;i<2;++i){
          if (i<nT){
            bf16x8 a=*(const bf16x8*)(actB+abase[i]+co+s*64);
            acc[i]=__builtin_amdgcn_mfma_f32_16x16x32_bf16(a,bh,acc[i],0,0,0);
            acc[i]=__builtin_amdgcn_mfma_f32_16x16x32_bf16(a,bl,acc[i],0,0,0);
          }
        }
      }
    }
    __syncthreads();   // all actA/PAT reads done -> safe to write c2s (aliases PATQ)
    #pragma unroll
    for (int i=0;i<2;++i){
      if (i<nT){
        int pos4=(w+i*4)*16+quad*4;
        if (pos4<100){
          float4* dst=(float4*)&c2s[l15][pos4];
          *dst=make_float4(acc[i].x*g2,acc[i].y*g2,acc[i].z*g2,acc[i].w*g2);
        }
      }
    }
  }
  __syncthreads();
  // fused: pool -> Y2P write + per-channel stats (shuffle-reduced, single pass)
  {
    const int ch=t>>4, g=t&15;
    const float* cc=&c2s[ch][0];
    float sum=0.f,sq=0.f,mn=3.4e38f,mx=-3.4e38f;
    #pragma unroll
    for (int it=0;it<2;++it){
      int j=g+it*16;
      if (j<25){
        int py=(j*52)>>8;            // j/5 for j<25
        int px=j-py*5;
        int base=py*20+px*2;
        float2 p0=*(const float2*)(cc+base);
        float2 p1=*(const float2*)(cc+base+10);
        float v=fmaxf(fmaxf(p0.x,p0.y),fmaxf(p1.x,p1.y));
        wsw[OFF_Y2P+(size_t)blk*400+ch*25+j]=v;
        sum+=v; sq=fmaf(v,v,sq); mn=fminf(mn,v); mx=fmaxf(mx,v);
      }
    }
    #pragma unroll
    for (int d=1;d<16;d<<=1){
      sum+=__shfl_xor(sum,d);
      sq +=__shfl_xor(sq,d);
      mn=fminf(mn,__shfl_xor(mn,d));
      mx=fmaxf(mx,__shfl_xor(mx,d));
    }
    if (g==0){
      float* p=wsw+OFF_ST2+((size_t)ch*NBC+blk)*4;
      p[0]=sum; p[1]=sq; p[2]=mn; p[3]=mx;
    }
  }
}

// ---------------- KE: bn2/relu/quant -> fc1 via MFMA -> relu; 256 blocks x 512 thr, 16 img, all 128 cols ----------------
__global__ __launch_bounds__(512) void ke_kernel(InPtrs in, const float* __restrict__ wsr, float* __restrict__ wsw){
  const int t=threadIdx.x, blk=blockIdx.x;
  __shared__ __align__(16) unsigned short xs[16*808];   // [img16][k_eff 800 + 8 pad] bf16 q codes (duplicated)
  __shared__ float sm[16], sisd[16];
  __shared__ float rwn[8], rwx[8];
  const unsigned* U=(const unsigned*)(wsr+OFF_GMM);
  const float lvf=(float)((1<<in.qb[0])-1);
  const float rmn=fdec(U[4]);
  const float rmx=fdec(U[5]);
  if (t<16){ sm[t]=wsr[OFF_BN2+t*4]; sisd[t]=1.0f/wsr[OFF_BN2+t*4+1]; }
  const float s3=(fmaxf(rmx,0.f)-fmaxf(rmn,0.f))/lvf;
  const float inv_s3=1.0f/s3;
  const float inv_s3w=1.0f/wsr[OFF_WSC+2];
  const int b0=blk*16;
  __syncthreads();
  // quantize 16 imgs x 400 k into LDS ONCE
  {
    const int img=t>>5, tg=t&31;
    const float* yrow=wsr+OFF_Y2P+(size_t)(b0+img)*400;
    unsigned* xsu=(unsigned*)xs;
    for (int n=0;n<13;++n){
      int k=n*32+tg;
      if (k<400){
        int ch=(k*5243)>>17;                          // k/25, exact for k<400
        float y=yrow[k];
        float r=fmaxf((y-sm[ch])*sisd[ch],0.f);
        float q=fminf(rintf(r*inv_s3),lvf);
        unsigned qb=__float_as_uint(q)>>16;           // exact: q is an integer <= 255
        xsu[img*404+k]=qb|(qb<<16);
      }
    }
  }
  __syncthreads();
  const int w=t>>6, lane=t&63, l15=lane&15, quad=lane>>4;
  const int ct=w;                                   // output col tile (16 cols), 8 waves cover 128
  const bf16x8* Wf=(const bf16x8*)(wsr+OFF_W3);
  const unsigned short* arow=xs+l15*808;
  f32x4 acc=(f32x4){0.f,0.f,0.f,0.f};
  #pragma unroll 5
  for (int kt=0;kt<25;++kt){
    bf16x8 a=*(const bf16x8*)(arow+kt*32+quad*8);
    bf16x8 b=Wf[(kt*8+ct)*64+lane];
    acc=__builtin_amdgcn_mfma_f32_16x16x32_bf16(a,b,acc,0,0,0);
  }
  const float scale=s3*inv_s3w;
  float hmn=3.4e38f,hmx=-3.4e38f;
  #pragma unroll
  for (int r=0;r<4;++r){
    float h=fmaxf(acc[r]*scale,0.f);
    wsw[OFF_H3+(size_t)(b0+quad*4+r)*128+ct*16+l15]=h;
    hmn=fminf(hmn,h); hmx=fmaxf(hmx,h);
  }
  #pragma unroll
  for (int d=1;d<64;d<<=1){
    hmn=fminf(hmn,__shfl_xor(hmn,d));
    hmx=fmaxf(hmx,__shfl_xor(hmx,d));
  }
  if (lane==0){ rwn[w]=hmn; rwx[w]=hmx; }
  __syncthreads();
  if (t==0){
    float mn=rwn[0], mx=rwx[0];
    #pragma unroll
    for (int i=1;i<8;++i){ mn=fminf(mn,rwn[i]); mx=fmaxf(mx,rwx[i]); }
    float* p=wsw+OFF_MMA+(size_t)blk*2;
    p[0]=mn; p[1]=mx;
  }
}

// ---------------- KF: reduce fc1 min/max partials -> quant -> fc2 -> log_softmax ----------------
__global__ __launch_bounds__(256) void kf_kernel(InPtrs in, const float* __restrict__ wsr, float* __restrict__ out){
  const int t=threadIdx.x, blk=blockIdx.x;
  __shared__ float w4s[1280];
  __shared__ float redn[256], redxs[256];
  const float lvf=(float)((1<<in.qb[0])-1);
  for (int i=t;i<1280;i+=256) w4s[i]=wsr[OFF_W4+i];
  // reduce the 256 per-block fc1 min/max partials (replaces global atomics in ke)
  {
    const float* mmp=wsr+OFF_MMA;
    float mn=3.4e38f, mx=-3.4e38f;
    if (t<NBE){
      mn=mmp[2*t];
      mx=mmp[2*t+1];
    }
    redn[t]=mn; redxs[t]=mx;
    __syncthreads();
    for (int s=128;s>0;s>>=1){
      if (t<s){ redn[t]=fminf(redn[t],redn[t+s]); redxs[t]=fmaxf(redxs[t],redxs[t+s]); }
      __syncthreads();
    }
  }
  const float hmn=redn[0];
  const float hmx=redxs[0];
  const float s4=(hmx-hmn)/lvf;
  const float inv_s4=1.0f/s4;
  const float inv_s4w=1.0f/wsr[OFF_WSC+3];
  const int row=blk*64+(t>>2), l4=t&3;
  const float4* hr4=(const float4*)(wsr+OFF_H3+(size_t)row*128);
  float acc[10];
  #pragma unroll
  for (int j=0;j<10;++j) acc[j]=0.f;
  #pragma unroll 2
  for (int j=0;j<8;++j){
    float4 v=hr4[l4*8+j];
    int kb=(l4*8+j)*4;
    float q0=fminf(rintf(v.x*inv_s4),lvf)*s4;
    float q1=fminf(rintf(v.y*inv_s4),lvf)*s4;
    float q2=fminf(rintf(v.z*inv_s4),lvf)*s4;
    float q3=fminf(rintf(v.w*inv_s4),lvf)*s4;
    #pragma unroll
    for (int o=0;o<10;++o){
      const float* wr=w4s+o*128+kb;
      acc[o]=fmaf(q0,wr[0],acc[o]);
      acc[o]=fmaf(q1,wr[1],acc[o]);
      acc[o]=fmaf(q2,wr[2],acc[o]);
      acc[o]=fmaf(q3,wr[3],acc[o]);
    }
  }
  #pragma unroll
  for (int o=0;o<10;++o){
    acc[o]+=__shfl_xor(acc[o],1);
    acc[o]+=__shfl_xor(acc[o],2);
  }
  if (l4==0){
    float mx=-3.4e38f;
    #pragma unroll
    for (int o=0;o<10;++o){ acc[o]*=inv_s4w; mx=fmaxf(mx,acc[o]); }
    float se=0.f;
    #pragma unroll
    for (int o=0;o<10;++o) se+=expf(acc[o]-mx);
    const float ls=logf(se);
    #pragma unroll
    for (int o=0;o<10;++o) out[row*10+o]=acc[o]-mx-ls;
  }
}

extern "C" void kernel_launch(void* const* d_in, const int* in_sizes, int n_in,
                              void* d_out, int out_size, void* d_ws, size_t ws_size,
                              hipStream_t stream){
  (void)in_sizes; (void)n_in; (void)out_size; (void)ws_size;
  InPtrs P;
  P.x=(const float*)d_in[0];
  for (int l=0;l<4;++l){
    P.sc[l]=(const float*)d_in[1+l*4];
    P.sg[l]=(const float*)d_in[2+l*4];
    P.on[l]=(const float*)d_in[3+l*4];
    P.ze[l]=(const float*)d_in[4+l*4];
  }
  P.qb=(const int*)d_in[17];
  float* ws=(float*)d_ws;

  hipLaunchKernelGGL(ka_kernel,   dim3(NBA+NBW), dim3(256), 0, stream, P, ws);
  hipLaunchKernelGGL(kwp2_kernel, dim3(NBW),     dim3(256), 0, stream, P, ws);
  hipLaunchKernelGGL(kwp3_kernel, dim3(NBW),     dim3(256), 0, stream, P, ws);
  hipLaunchKernelGGL(kw3_kernel,  dim3(NBW),     dim3(256), 0, stream, P, ws);
  hipLaunchKernelGGL(kb_kernel,   dim3(NBB),     dim3(256), 0, stream, P, ws, ws);
  hipLaunchKernelGGL(kstat_kernel, dim3(64), dim3(256), 0, stream, ws, ws,
                     (unsigned long long)OFF_ST1, NBB, 4096.f*144.f, (unsigned long long)OFF_BN1, 2);
  hipLaunchKernelGGL(kc_kernel,   dim3(NBC/2),   dim3(256), 0, stream, P, ws, ws, 0);
  hipLaunchKernelGGL(kc_kernel,   dim3(NBC/2),   dim3(256), 0, stream, P, ws, ws, NBC/2);
  hipLaunchKernelGGL(kstat_kernel, dim3(16), dim3(256), 0, stream, ws, ws,
                     (unsigned long long)OFF_ST2, NBC, 4096.f*25.f, (unsigned long long)OFF_BN2, 4);
  hipLaunchKernelGGL(ke_kernel,   dim3(NBE),     dim3(512), 0, stream, P, ws, ws);
  hipLaunchKernelGGL(kf_kernel,   dim3(64),      dim3(256), 0, stream, P, ws, (float*)d_out);
}

// Round 14
// 225.136 us; speedup vs baseline: 1.0476x; 1.0476x over previous
//
#include <hip/hip_runtime.h>
#include <hip/hip_bf16.h>
#include <math.h>

#define DEV __device__ __forceinline__

constexpr int BATCH = 4096;
constexpr int NBA = 512;    // pool blocks, 8 img each (ka also carries 16 hist blocks)
constexpr int NBB = 1024;   // conv1-stats blocks (4 img each, ONE WAVE PER IMAGE, barrier-free)
constexpr int NBC = 4096;   // fused conv blocks (1 img each)
constexpr int NBE = 256;    // fc1 blocks (16 img each, 512 threads, all 128 cols)
constexpr int NBW = 16;     // hist slices

// workspace layout (float offsets)
constexpr size_t OFF_POOLED = 0;                            // 4096*196
constexpr size_t OFF_Y2P = OFF_POOLED + (size_t)BATCH*196;  // 4096*400
constexpr size_t OFF_ST1 = OFF_Y2P;                         // 64*1024*4; consumed by kstat1 BEFORE kc writes Y2P
constexpr size_t OFF_H3  = OFF_Y2P + (size_t)BATCH*400;     // 4096*128
constexpr size_t OFF_ST2 = OFF_H3;                          // 16*4096*4; consumed by kstat2 BEFORE ke writes H3
constexpr size_t OFF_W2  = OFF_H3 + (size_t)BATCH*128;      // W2F u16[9][2][2][4][16][8] lane-linear
constexpr size_t OFF_W3  = OFF_W2 + 9216;                   // W3F u16: [kt25][ct8][lane64][8] hi/lo K-interleaved (51200 f32 exactly)
constexpr size_t OFF_W4  = OFF_W3 + 51200;                  // 1280 [oc*128+k]
constexpr size_t OFF_WSC = OFF_W4 + 1280;                   // 4 layer scales
constexpr size_t OFF_BN1 = OFF_WSC + 4;                     // 64*4
constexpr size_t OFF_BN2 = OFF_BN1 + 256;                   // 16*4
constexpr size_t OFF_GMM = OFF_BN2 + 64;                    // 8 encoded slots
constexpr size_t OFF_ONS = OFF_GMM + 8;                     // 16 per-slice sum(hw_one)
constexpr size_t OFF_T   = OFF_ONS + 16;                    // (unused)
constexpr size_t OFF_MMA = OFF_T + 4;                       // 512*2 pooled min/max partials; REUSED by ke for fc1 min/max partials
constexpr size_t OFF_HIST= OFF_MMA + 1024;                  // 16*2048 per-slice pass-1 histograms
constexpr size_t OFF_W1M = OFF_HIST + 32768;                // W1F u16[4][2][4][16][8] (2048 floats)
constexpr size_t OFF_SEL = OFF_W1M + 2048;                  // 8 uints: per-L {b0, r1}
constexpr size_t OFF_H2G = OFF_SEL + 8;                     // 4*1024 uints pass-2 global hists
constexpr size_t OFF_H3G = OFF_H2G + 4096;                  // 4*1024 uints pass-3 global hists
// GMM: [0]=pooled min [1]=pooled max [2]=bn1 tmin [3]=bn1 tmax [4]=bn2 tmin [5]=bn2 tmax [6,7]=unused
// NOTE (r5): cooperative grid.sync() on MI355X cost ~17us/sync at 16 blocks -- tiny launches are CHEAPER.
// NOTE (r7): kc 2-img/block -> VGPR 52->96 -> occupancy halved -> +11us. Occupancy > L1 reuse here.
// NOTE (r9/r12): kc flat ~45.5us across 4 structural variants -> per-block critical-path floor; parked.
// NOTE (r13 probe): harness re-poison memset (256MiB fillBuffer, ~42us @80% HBM) is INSIDE the timed
//       region and untouchable; no other hidden kernel exceeds ~23us. kc split cost +4.5us -> reverted.

typedef __attribute__((ext_vector_type(8))) short bf16x8;
typedef __attribute__((ext_vector_type(4))) float f32x4;

struct InPtrs {
  const float* x;
  const float* sc[4];
  const float* sg[4];
  const float* on[4];
  const float* ze[4];
  const int* qb;
};

// hist-slice partition: 16 slices over 4 layers
__constant__ const int KW_L[16]  ={0,1,1,2,2,2,2,2,2,2,2,2,2,2,2,3};
__constant__ const int KW_S[16]  ={0,0,1,0,1,2,3,4,5,6,7,8,9,10,11,0};
__constant__ const int KW_NB[4]  ={1,2,12,1};
__constant__ const int KW_N[4]   ={576,9216,51200,1280};
__constant__ const int KW_FAN[4] ={9,576,400,128};
__constant__ const int KW_BW0[4] ={0,1,3,15};
__constant__ const int KW_BW1[4] ={1,3,15,16};

DEV unsigned fenc(float f){ unsigned u=__float_as_uint(f); return (u&0x80000000u)? ~u : (u|0x80000000u); }
DEV float fdec(unsigned e){ return __uint_as_float((e&0x80000000u)? (e&0x7fffffffu) : ~e); }
DEV unsigned short f2bf(float f){ unsigned u=__float_as_uint(f); return (unsigned short)((u + 0x7fffu + ((u>>16)&1u))>>16); }

DEV float blk_sum(float v, float* red, int t){
  red[t]=v; __syncthreads();
  for (int s=128;s>0;s>>=1){ if(t<s) red[t]+=red[t+s]; __syncthreads(); }
  float r=red[0]; __syncthreads();
  return r;
}
DEV float blk_min(float v, float* red, int t){
  red[t]=v; __syncthreads();
  for (int s=128;s>0;s>>=1){ if(t<s) red[t]=fminf(red[t],red[t+s]); __syncthreads(); }
  float r=red[0]; __syncthreads();
  return r;
}
DEV float blk_max(float v, float* red, int t){
  red[t]=v; __syncthreads();
  for (int s=128;s>0;s>>=1){ if(t<s) red[t]=fmaxf(red[t],red[t+s]); __syncthreads(); }
  float r=red[0]; __syncthreads();
  return r;
}

// find bucket from top with 256 threads; nbins in {1024,2048}; returns {bucket, remainder}
DEV int2 find256(const int* hist, int nbins, int kk, int t, int* suf, int* sh2){
  const int G=nbins>>8;
  const int lo=t*G;
  int g=0;
  for (int b=0;b<G;++b) g+=hist[lo+b];
  suf[t]=g; __syncthreads();
  for (int s=1;s<256;s<<=1){
    int add=(t+s<256)?suf[t+s]:0;
    __syncthreads();
    suf[t]+=add;
    __syncthreads();
  }
  const int S=suf[t];
  const int Snext=(t<255)?suf[t+1]:0;
  if (S>=kk && Snext<kk){
    int c2=Snext;
    for (int b=lo+G-1;b>=lo;--b){
      c2+=hist[b];
      if (c2>=kk){ sh2[0]=b; sh2[1]=kk-(c2-hist[b]); break; }
    }
  }
  __syncthreads();
  int2 r=make_int2(sh2[0],sh2[1]);
  __syncthreads();
  return r;
}

// ---------------- KA: blocks<512: maxpool (8 img/block, div-free) + min/max partials
//                    (block0 also zeroes pass2/3 hists). blocks 512..527: per-slice pass-1 hist + sum(hw_one).
__global__ __launch_bounds__(256) void ka_kernel(InPtrs in, float* __restrict__ ws){
  const int t=threadIdx.x, blk=blockIdx.x;
  __shared__ int h[2048];
  __shared__ float red[256];
  if (blk<NBA){
    if (blk==0){
      unsigned* Z=(unsigned*)(ws+OFF_H2G);
      for (int i=t;i<8192;i+=256) Z[i]=0u;
    }
    const float* x=in.x;
    float* pooled=ws+OFF_POOLED;
    float lmn=3.4e38f, lmx=-3.4e38f;
    if (t<196){
      const int oy=(t*2341)>>15;       // t/14, exact for t<196
      const int ox=t-oy*14;
      const float* xb=x+(size_t)blk*8*784+oy*56+ox*2;
      #pragma unroll
      for (int im=0; im<8; ++im){
        const float* px=xb+im*784;
        float m=fmaxf(fmaxf(px[0],px[1]),fmaxf(px[28],px[29]));
        pooled[(size_t)(blk*8+im)*196+t]=m;
        lmn=fminf(lmn,m); lmx=fmaxf(lmx,m);
      }
    }
    float bmn=blk_min(lmn,red,t);
    float bmx=blk_max(lmx,red,t);
    if (t==0){ ws[OFF_MMA+blk*2]=bmn; ws[OFF_MMA+blk*2+1]=bmx; }
  } else {
    const int bw=blk-NBA;
    const int L=KW_L[bw], s=KW_S[bw], nb=KW_NB[L];
    const int n4=KW_N[L]>>2;
    const int lo=(int)(((long long)n4*s)/nb), hi=(int)(((long long)n4*(s+1))/nb);
    const float4* sc4=(const float4*)in.sc[L];
    const float4* on4=(const float4*)in.on[L];
    for (int i=t;i<2048;i+=256) h[i]=0;
    __syncthreads();
    float onsum=0.f;
    for (int i=lo+t;i<hi;i+=256){
      float4 v=sc4[i];
      atomicAdd(&h[(__float_as_uint(v.x)&0x7fffffffu)>>20],1);
      atomicAdd(&h[(__float_as_uint(v.y)&0x7fffffffu)>>20],1);
      atomicAdd(&h[(__float_as_uint(v.z)&0x7fffffffu)>>20],1);
      atomicAdd(&h[(__float_as_uint(v.w)&0x7fffffffu)>>20],1);
      float4 o=on4[i];
      onsum+=(o.x+o.y)+(o.z+o.w);
    }
    __syncthreads();
    unsigned* GH=(unsigned*)(ws+OFF_HIST);
    for (int i=t;i<2048;i+=256) GH[bw*2048+i]=(unsigned)h[i];
    float S=blk_sum(onsum,red,t);
    if (t==0) ws[OFF_ONS+bw]=S;
  }
}

// ---------------- KWP2: (absorbed kw2a) per-block: merge pass-1 hists + find (b0,r1) for own L;
// block0: pooled reduce + GMM init; block15: W1F zero; then pass-2 conditional histogram ----------------
__global__ __launch_bounds__(256) void kwp2_kernel(InPtrs in, float* __restrict__ ws){
  const int t=threadIdx.x, bw=blockIdx.x;
  __shared__ int hist[2048];
  __shared__ int suf[256];
  __shared__ int sh2[2];
  __shared__ float redm[256], redx[256];
  const int L=KW_L[bw], s=KW_S[bw], nb=KW_NB[L];
  const int n4=KW_N[L]>>2;
  const int lo=(int)(((long long)n4*s)/nb), hi=(int)(((long long)n4*(s+1))/nb);
  if (bw==0){
    float a0=ws[OFF_MMA+2*t],       a1=ws[OFF_MMA+2*(t+256)];
    float b0v=ws[OFF_MMA+2*t+1],    b1v=ws[OFF_MMA+2*(t+256)+1];
    redm[t]=fminf(a0,a1); redx[t]=fmaxf(b0v,b1v);
    __syncthreads();
    for (int st=128;st>0;st>>=1){
      if (t<st){ redm[t]=fminf(redm[t],redm[t+st]); redx[t]=fmaxf(redx[t],redx[t+st]); }
      __syncthreads();
    }
    unsigned* U=(unsigned*)(ws+OFF_GMM);
    if (t==0){ U[0]=fenc(redm[0]); U[1]=fenc(redx[0]); }
    if (t>=2 && t<8) U[t]=(t&1)? 0u : 0xFFFFFFFFu;
    __syncthreads();
  }
  if (bw==15){
    unsigned* z=(unsigned*)(ws+OFF_W1M);     // zero W1F (k>=9 pads); consumed by kw3 (2 launches later)
    for (int i=t;i<2048;i+=256) z[i]=0u;
  }
  // merged pass-1 hist for this block's L + find1 (each block recomputes -- cheap, removes a launch)
  const unsigned* GH=(const unsigned*)(ws+OFF_HIST);
  for (int i=t;i<2048;i+=256){
    int sm=0;
    for (int b2=KW_BW0[L]; b2<KW_BW1[L]; ++b2) sm+=(int)GH[b2*2048+i];
    hist[i]=sm;
  }
  __syncthreads();
  int2 f1=find256(hist,2048,KW_N[L]>>1,t,suf,sh2);
  const unsigned b0=(unsigned)f1.x;
  if (s==0 && t==0){
    unsigned* SEL=(unsigned*)(ws+OFF_SEL);
    SEL[L*2]=(unsigned)f1.x; SEL[L*2+1]=(unsigned)f1.y;
  }
  // pass-2 hist (bits [19:10])
  const float4* sc4=(const float4*)in.sc[L];
  unsigned* GH2=(unsigned*)(ws+OFF_H2G)+L*1024;
  for (int i=lo+t;i<hi;i+=256){
    float4 v=sc4[i];
    unsigned ux=__float_as_uint(v.x)&0x7fffffffu;
    unsigned uy=__float_as_uint(v.y)&0x7fffffffu;
    unsigned uz=__float_as_uint(v.z)&0x7fffffffu;
    unsigned uw=__float_as_uint(v.w)&0x7fffffffu;
    if ((ux>>20)==b0) atomicAdd(&GH2[(ux>>10)&1023u],1u);
    if ((uy>>20)==b0) atomicAdd(&GH2[(uy>>10)&1023u],1u);
    if ((uz>>20)==b0) atomicAdd(&GH2[(uz>>10)&1023u],1u);
    if ((uw>>20)==b0) atomicAdd(&GH2[(uw>>10)&1023u],1u);
  }
}

// ---------------- KWP3: per-block find (b1,r2) over hist2, then pass-3 conditional histogram ----------------
__global__ __launch_bounds__(256) void kwp3_kernel(InPtrs in, float* __restrict__ ws){
  const int t=threadIdx.x, bw=blockIdx.x;
  const int L=KW_L[bw], s=KW_S[bw], nb=KW_NB[L];
  const int n4=KW_N[L]>>2;
  const int lo=(int)(((long long)n4*s)/nb), hi=(int)(((long long)n4*(s+1))/nb);
  const unsigned* SEL=(const unsigned*)(ws+OFF_SEL);
  const unsigned b0=SEL[L*2]; const int r1=(int)SEL[L*2+1];
  __shared__ int hist[1024];
  __shared__ int suf[256];
  __shared__ int sh2[2];
  const unsigned* GH2=(const unsigned*)(ws+OFF_H2G)+L*1024;
  for (int i=t;i<1024;i+=256) hist[i]=(int)GH2[i];
  __syncthreads();
  int2 f2=find256(hist,1024,r1,t,suf,sh2);
  const unsigned pre=(b0<<10)|(unsigned)f2.x;
  const float4* sc4=(const float4*)in.sc[L];
  unsigned* GH3=(unsigned*)(ws+OFF_H3G)+L*1024;
  for (int i=lo+t;i<hi;i+=256){
    float4 v=sc4[i];
    unsigned ux=__float_as_uint(v.x)&0x7fffffffu;
    unsigned uy=__float_as_uint(v.y)&0x7fffffffu;
    unsigned uz=__float_as_uint(v.z)&0x7fffffffu;
    unsigned uw=__float_as_uint(v.w)&0x7fffffffu;
    if ((ux>>10)==pre) atomicAdd(&GH3[ux&1023u],1u);
    if ((uy>>10)==pre) atomicAdd(&GH3[uy&1023u],1u);
    if ((uz>>10)==pre) atomicAdd(&GH3[uz&1023u],1u);
    if ((uw>>10)==pre) atomicAdd(&GH3[uw&1023u],1u);
  }
}

// ---------------- KW3: per-block finds -> exact T; slice-parallel weight writes ----------------
__global__ __launch_bounds__(256) void kw3_kernel(InPtrs in, float* __restrict__ ws){
  const int t=threadIdx.x, bw=blockIdx.x;
  const int L=KW_L[bw], s=KW_S[bw], nb=KW_NB[L];
  const int n4=KW_N[L]>>2;
  const int lo=(int)(((long long)n4*s)/nb), hi=(int)(((long long)n4*(s+1))/nb);
  const unsigned* SEL=(const unsigned*)(ws+OFF_SEL);
  const unsigned b0=SEL[L*2]; const int r1=(int)SEL[L*2+1];
  __shared__ int hist[1024];
  __shared__ int suf[256];
  __shared__ int sh2[2];
  const unsigned* GH2=(const unsigned*)(ws+OFF_H2G)+L*1024;
  for (int i=t;i<1024;i+=256) hist[i]=(int)GH2[i];
  __syncthreads();
  int2 f2=find256(hist,1024,r1,t,suf,sh2);
  const unsigned pre=(b0<<10)|(unsigned)f2.x;
  const int r2=f2.y;
  __syncthreads();
  const unsigned* GH3=(const unsigned*)(ws+OFF_H3G)+L*1024;
  for (int i=t;i<1024;i+=256) hist[i]=(int)GH3[i];
  __syncthreads();
  int2 f3=find256(hist,1024,r2,t,suf,sh2);
  const unsigned T=(pre<<10)|(unsigned)f3.x;
  if (s==0 && t==0){
    float os=0.f;
    for (int b=KW_BW0[L]; b<KW_BW1[L]; ++b) os+=ws[OFF_ONS+b];
    ws[OFF_WSC+L]=(os/(float)KW_N[L])*sqrtf((float)KW_FAN[L])*0.5f;
  }
  const float4* sc4=(const float4*)in.sc[L];
  const float4* sg4=(const float4*)in.sg[L];
  const float4* on4=(const float4*)in.on[L];
  const float4* ze4=(const float4*)in.ze[L];
  float* wout=ws+OFF_W4;
  unsigned* W3Fu=(unsigned*)(ws+OFF_W3);               // fc1 MFMA layout, hi/lo K-interleaved
  unsigned short* W1F=(unsigned short*)(ws+OFF_W1M);   // [ocT][h][quad][oc16][8]
  unsigned short* W2F=(unsigned short*)(ws+OFF_W2);    // [kykx][s][h][quad][oc16][8]
  for (int i4=lo+t;i4<hi;i4+=256){
    float4 sv4=sc4[i4], g=sg4[i4], o=on4[i4], z=ze4[i4];
    float sv[4]={sv4.x,sv4.y,sv4.z,sv4.w}, gv[4]={g.x,g.y,g.z,g.w};
    float ov[4]={o.x,o.y,o.z,o.w}, zv[4]={z.x,z.y,z.z,z.w};
    #pragma unroll
    for (int j=0;j<4;++j){
      int i=i4*4+j;
      unsigned u=__float_as_uint(sv[j])&0x7fffffffu;
      float w=gv[j]*((u>=T)? ov[j] : zv[j]);
      if (L==0){
        int oc=i/9; int k=i-oc*9;
        int ocT=oc>>4, ocL=oc&15, quad=k>>3, kj=k&7;
        unsigned short hb=f2bf(w);
        float lo2=w-__uint_as_float((unsigned)hb<<16);
        W1F[((((ocT*2+0)*4+quad)*16+ocL)<<3)+kj]=hb;
        W1F[((((ocT*2+1)*4+quad)*16+ocL)<<3)+kj]=f2bf(lo2);
      } else if (L==1){
        int oc=i/576; int r=i-oc*576; int ic=r/9; int kp=r-ic*9;
        int ss=ic>>5, rem=ic&31, quad=rem>>3, kj=rem&7;
        unsigned short hb=f2bf(w);
        float lo2=w-__uint_as_float((unsigned)hb<<16);
        W2F[(((((kp*2+ss)*2+0)*4+quad)*16+oc)<<3)+kj]=hb;
        W2F[(((((kp*2+ss)*2+1)*4+quad)*16+oc)<<3)+kj]=f2bf(lo2);
      } else if (L==2){
        // fc1 weight: oc in [0,128), kk in [0,400). k_eff = 2*kk (+1 for lo half).
        int oc=i/400; int kk=i-oc*400;
        unsigned short hb=f2bf(w);
        float lo2=w-__uint_as_float((unsigned)hb<<16);
        unsigned short lb=f2bf(lo2);
        int ct=oc>>4, l15=oc&15;
        unsigned idx=((unsigned)((kk>>4)*8+ct)*64u + (unsigned)(((kk>>2)&3)*16+l15))*4u + (unsigned)(kk&3);
        W3Fu[idx]=(unsigned)hb | ((unsigned)lb<<16);
      } else {
        wout[i]=w;
      }
    }
  }
}

// ---------------- KB: conv1 via MFMA -> BN1 stats partials. 1024 blocks x 4 img, ONE WAVE PER IMAGE.
// r14: wave-independent -- each wave owns its image's qxs+PATQ (wave-local LDS, ordered by lgkmcnt,
// NO __syncthreads in the per-image pipeline). Single barrier at the final cross-wave stat reduce.
__global__ __launch_bounds__(256) void kb_kernel(InPtrs in, const float* __restrict__ wsr, float* __restrict__ wsw){
  const int t=threadIdx.x, blk=blockIdx.x;
  const int w=t>>6, lane=t&63, l15=lane&15, quad=lane>>4;
  __shared__ unsigned short qxsW[4][256];
  __shared__ __align__(16) unsigned PATW[4][2304];   // per-wave PATQ[quad][pos144][4 dw]
  __shared__ float xw[1024];
  const float* pooled=wsr+OFF_POOLED;
  const unsigned* U=(const unsigned*)(wsr+OFF_GMM);
  const float mn0=fdec(U[0]);
  const float mx0=fdec(U[1]);
  const float lvf=(float)((1<<in.qb[0])-1);
  const float s0=(mx0-mn0)/lvf, inv_s0=1.0f/s0, zp0=floorf(mn0/s0);
  const float sv=s0/wsr[OFF_WSC+0];
  const unsigned short* W1F=(const unsigned short*)(wsr+OFF_W1M);
  const int img=blk*4+w;
  // zero own planes 2,3 (k16..31)
  for (int i=1152+lane; i<2304; i+=64) PATW[w][i]=0u;
  // quantize own image's pooled 14x14 into qxsW[w] (16x16, col<14 guard)
  for (int i=lane; i<224; i+=64){
    int row=i>>4, col=i&15;
    float q=0.f;
    if (col<14){ float xx=pooled[(size_t)img*196+row*14+col]; q=rintf((xx-mn0)*inv_s0)+zp0; }
    qxsW[w][i]=(unsigned short)(__float_as_uint(q)>>16);
  }
  // build own PATQ (wave-local; lgkmcnt orders ds_write->ds_read within the wave)
  for (int pos=lane; pos<144; pos+=64){
    int py=(pos*171)>>11;          // pos/12 for pos<144
    int px=pos-py*12;
    const unsigned short* q0=&qxsW[w][py*16+px];
    unsigned e0=q0[0],  e1=q0[1],  e2=q0[2];
    unsigned e3=q0[16], e4=q0[17], e5=q0[18];
    unsigned e6=q0[32], e7=q0[33], e8=q0[34];
    *(uint4*)(&PATW[w][pos*4])      =make_uint4(e0|(e1<<16), e2|(e3<<16), e4|(e5<<16), e6|(e7<<16));
    *(uint4*)(&PATW[w][(144+pos)*4])=make_uint4(e8, 0u, 0u, 0u);
  }
  // conv1: this wave does ALL 9 tiles x 4 ocT (72 MFMA), stats in regs -- no barriers
  const unsigned short* PATu=(const unsigned short*)PATW[w];
  float sum[4], sq[4], mn[4], mx[4];
  #pragma unroll
  for (int i=0;i<4;++i){ sum[i]=0.f; sq[i]=0.f; mn[i]=3.4e38f; mx[i]=-3.4e38f; }
  #pragma unroll
  for (int ocT=0; ocT<4; ++ocT){
    bf16x8 bh=*(const bf16x8*)(W1F+(((ocT*2+0)*64+lane)<<3));
    bf16x8 bl=*(const bf16x8*)(W1F+(((ocT*2+1)*64+lane)<<3));
    for (int tl=0; tl<9; ++tl){
      bf16x8 a=*(const bf16x8*)(PATu+((quad*144+tl*16+l15)<<3));
      f32x4 acc=(f32x4){0.f,0.f,0.f,0.f};
      acc=__builtin_amdgcn_mfma_f32_16x16x32_bf16(a,bh,acc,0,0,0);
      acc=__builtin_amdgcn_mfma_f32_16x16x32_bf16(a,bl,acc,0,0,0);
      #pragma unroll
      for (int r=0;r<4;++r){
        float v=acc[r];
        sum[ocT]+=v; sq[ocT]=fmaf(v,v,sq[ocT]);
        mn[ocT]=fminf(mn[ocT],v); mx[ocT]=fmaxf(mx[ocT],v);
      }
    }
  }
  // wave reduce, cross-wave combine (single barrier), store partials
  #pragma unroll
  for (int ocT=0; ocT<4; ++ocT){
    float s=sum[ocT], q2=sq[ocT], a=mn[ocT], b=mx[ocT];
    #pragma unroll
    for (int d=16;d<64;d<<=1){
      s+=__shfl_xor(s,d);
      q2+=__shfl_xor(q2,d);
      a=fminf(a,__shfl_xor(a,d));
      b=fmaxf(b,__shfl_xor(b,d));
    }
    if (quad==0){
      float* p=xw+((w*4+ocT)*16+l15)*4;
      p[0]=s; p[1]=q2; p[2]=a; p[3]=b;
    }
  }
  __syncthreads();
  if (t<64){
    float s=0.f,q2=0.f,a=3.4e38f,b=-3.4e38f;
    #pragma unroll
    for (int w2=0;w2<4;++w2){
      const float* p=xw+((w2*4+(t>>4))*16+(t&15))*4;
      s+=p[0]; q2+=p[1]; a=fminf(a,p[2]); b=fmaxf(b,p[3]);
    }
    float* p=wsw+OFF_ST1+((size_t)t*NBB+blk)*4;
    p[0]=s*sv; p[1]=q2*sv*sv; p[2]=a*sv; p[3]=b*sv;
  }
}

// ---------------- kstat ----------------
__global__ __launch_bounds__(256) void kstat_kernel(const float* __restrict__ wsr, float* __restrict__ wsw,
                                                    unsigned long long inoff, int nparts, float Nf,
                                                    unsigned long long outoff, int mmslot){
  const int c=blockIdx.x, t=threadIdx.x;
  __shared__ float red[256];
  const float* p=wsr+inoff+(size_t)c*nparts*4;
  float sum=0.f,sq=0.f,mn=3.4e38f,mx=-3.4e38f;
  for (int i=t;i<nparts;i+=256){
    sum+=p[i*4]; sq+=p[i*4+1];
    mn=fminf(mn,p[i*4+2]); mx=fmaxf(mx,p[i*4+3]);
  }
  float S=blk_sum(sum,red,t);
  float Q=blk_sum(sq,red,t);
  float MN=blk_min(mn,red,t);
  float MX=blk_max(mx,red,t);
  if (t==0){
    float mean=S/Nf;
    float var=fmaxf(Q/Nf-mean*mean,0.f);
    float sd=sqrtf(var+1e-5f);
    float* o=wsw+outoff+c*4;
    float tmn=(MN-mean)/sd, tmx=(MX-mean)/sd;
    o[0]=mean; o[1]=sd; o[2]=tmn; o[3]=tmx;
    unsigned* U=(unsigned*)(wsw+OFF_GMM);
    atomicMin(&U[mmslot],fenc(tmn));
    atomicMax(&U[mmslot+1],fenc(tmx));
  }
}

// ---------------- KC: conv1(MFMA)->bn1/relu/quant->conv2(MFMA)->pool, 1 img/block ----------------
// conv1 operands SWAPPED (mfma(W,P)); PATQ conflict-free layout; 31KB LDS -> 5 blocks/CU. Parked.
__global__ __launch_bounds__(256) void kc_kernel(InPtrs in, const float* __restrict__ wsr, float* __restrict__ wsw){
  const int t=threadIdx.x, blk=blockIdx.x;
  __shared__ unsigned short qxs[256];
  __shared__ __align__(16) unsigned PATBUF[2304];        // PATQ (2304 dw) aliased by c2s[16][100] (1600 dw)
  __shared__ __align__(16) unsigned short actA[144*72];  // [cell][72: 64 ch + 8 pad] bf16 codes, 144B rows
  __shared__ float sA2[64], sB2[64];
  unsigned* PAT=PATBUF;
  float (*c2s)[100]=(float(*)[100])PATBUF;
  const float* pooled=wsr+OFF_POOLED;
  const unsigned* U=(const unsigned*)(wsr+OFF_GMM);
  const float mn0=fdec(U[0]);
  const float mx0=fdec(U[1]);
  const float rmn=fdec(U[2]);
  const float rmx=fdec(U[3]);
  const float lvf=(float)((1<<in.qb[0])-1);
  const float s0=(mx0-mn0)/lvf, inv_s0=1.0f/s0, zp0=floorf(mn0/s0);
  const float s1w=wsr[OFF_WSC+0], s2w=wsr[OFF_WSC+1];
  const float s2=(fmaxf(rmx,0.f)-fmaxf(rmn,0.f))/lvf;
  const float inv_s2=1.0f/s2;
  const float g2=s2/s2w;
  if (t<64){
    float m=wsr[OFF_BN1+t*4], sd=wsr[OFF_BN1+t*4+1];
    sA2[t]=s0/(s1w*sd)*inv_s2;
    sB2[t]=(-m/sd)*inv_s2;
  }
  if (t<224){
    int row=t>>4, col=t&15;
    float q=0.f;
    if (col<14){ float xx=pooled[(size_t)blk*196+row*14+col]; q=rintf((xx-mn0)*inv_s0)+zp0; }
    qxs[t]=(unsigned short)(__float_as_uint(q)>>16);
  }
  for (int i=1152+t; i<2304; i+=256) PAT[i]=0u;   // zero PATQ planes 2,3
  __syncthreads();
  for (int pos=t; pos<144; pos+=256){
    int py=(pos*171)>>11;          // pos/12 for pos<144
    int px=pos-py*12;
    const unsigned short* q0=qxs+py*16+px;
    unsigned e0=q0[0],  e1=q0[1],  e2=q0[2];
    unsigned e3=q0[16], e4=q0[17], e5=q0[18];
    unsigned e6=q0[32], e7=q0[33], e8=q0[34];
    *(uint4*)(PAT+pos*4)      =make_uint4(e0|(e1<<16), e2|(e3<<16), e4|(e5<<16), e6|(e7<<16));
    *(uint4*)(PAT+(144+pos)*4)=make_uint4(e8, 0u, 0u, 0u);
  }
  __syncthreads();
  const int w=t>>6, lane=t&63;
  const int l15=lane&15, quad=lane>>4;
  // conv1 MFMA (swapped) + bn/relu/quant -> actA via packed b64
  {
    const unsigned short* W1F=(const unsigned short*)(wsr+OFF_W1M);
    const unsigned short* PATu=(const unsigned short*)PAT;
    #pragma unroll
    for (int ocT=0; ocT<4; ++ocT){
      bf16x8 bh=*(const bf16x8*)(W1F+(((ocT*2+0)*64+lane)<<3));
      bf16x8 bl=*(const bf16x8*)(W1F+(((ocT*2+1)*64+lane)<<3));
      const int oc0=ocT*16+quad*4;
      const float a20=sA2[oc0],   b20=sB2[oc0];
      const float a21=sA2[oc0+1], b21=sB2[oc0+1];
      const float a22=sA2[oc0+2], b22=sB2[oc0+2];
      const float a23=sA2[oc0+3], b23=sB2[oc0+3];
      for (int tl=w; tl<9; tl+=4){
        bf16x8 a=*(const bf16x8*)(PATu+((quad*144+tl*16+l15)<<3));
        f32x4 acc=(f32x4){0.f,0.f,0.f,0.f};
        acc=__builtin_amdgcn_mfma_f32_16x16x32_bf16(bh,a,acc,0,0,0);
        acc=__builtin_amdgcn_mfma_f32_16x16x32_bf16(bl,a,acc,0,0,0);
        const int pos=tl*16+l15;
        float f0=fminf(rintf(fmaxf(fmaf(acc[0],a20,b20),0.f)),lvf);
        float f1=fminf(rintf(fmaxf(fmaf(acc[1],a21,b21),0.f)),lvf);
        float f2v=fminf(rintf(fmaxf(fmaf(acc[2],a22,b22),0.f)),lvf);
        float f3=fminf(rintf(fmaxf(fmaf(acc[3],a23,b23),0.f)),lvf);
        unsigned w0=(__float_as_uint(f0)>>16)|((__float_as_uint(f1)>>16)<<16);
        unsigned w1=(__float_as_uint(f2v)>>16)|((__float_as_uint(f3)>>16)<<16);
        *(uint2*)(actA+pos*72+oc0)=make_uint2(w0,w1);
      }
    }
  }
  __syncthreads();
  // conv2 via MFMA: 7 M-tiles of 16 positions; wave w owns taus {w, w+4}
  {
    const int nT=(w<3)?2:1;
    const unsigned short* W2F=(const unsigned short*)(wsr+OFF_W2);
    int abase[2];
    #pragma unroll
    for (int i=0;i<2;++i){
      int tau=w+i*4;
      int posb=tau*16+l15;
      int pc=posb>99?99:posb;
      int py=pc/10, px=pc-py*10;
      abase[i]=(py*12+px)*144+quad*16;   // BYTE offset in actA
    }
    f32x4 acc[2];
    acc[0]=(f32x4){0.f,0.f,0.f,0.f};
    acc[1]=(f32x4){0.f,0.f,0.f,0.f};
    const char* actB=(const char*)actA;
    #pragma unroll 3
    for (int kykx=0;kykx<9;++kykx){
      int ky=(kykx*11)>>5;           // kykx/3 for kykx<9
      int kx=kykx-ky*3;
      int co=(ky*12+kx)*144;
      #pragma unroll
      for (int s=0;s<2;++s){
        bf16x8 bh=*(const bf16x8*)(W2F+((((kykx*2+s)*2+0)*64+lane)<<3));
        bf16x8 bl=*(const bf16x8*)(W2F+((((kykx*2+s)*2+1)*64+lane)<<3));
        #pragma unroll
        for (int i=0;i<2;++i){
          if (i<nT){
            bf16x8 a=*(const bf16x8*)(actB+abase[i]+co+s*64);
            acc[i]=__builtin_amdgcn_mfma_f32_16x16x32_bf16(a,bh,acc[i],0,0,0);
            acc[i]=__builtin_amdgcn_mfma_f32_16x16x32_bf16(a,bl,acc[i],0,0,0);
          }
        }
      }
    }
    __syncthreads();   // all actA/PAT reads done -> safe to write c2s (aliases PATQ)
    #pragma unroll
    for (int i=0;i<2;++i){
      if (i<nT){
        int pos4=(w+i*4)*16+quad*4;
        if (pos4<100){
          float4* dst=(float4*)&c2s[l15][pos4];
          *dst=make_float4(acc[i].x*g2,acc[i].y*g2,acc[i].z*g2,acc[i].w*g2);
        }
      }
    }
  }
  __syncthreads();
  // fused: pool -> Y2P write + per-channel stats (shuffle-reduced, single pass)
  {
    const int ch=t>>4, g=t&15;
    const float* cc=&c2s[ch][0];
    float sum=0.f,sq=0.f,mn=3.4e38f,mx=-3.4e38f;
    #pragma unroll
    for (int it=0;it<2;++it){
      int j=g+it*16;
      if (j<25){
        int py=(j*52)>>8;            // j/5 for j<25
        int px=j-py*5;
        int base=py*20+px*2;
        float2 p0=*(const float2*)(cc+base);
        float2 p1=*(const float2*)(cc+base+10);
        float v=fmaxf(fmaxf(p0.x,p0.y),fmaxf(p1.x,p1.y));
        wsw[OFF_Y2P+(size_t)blk*400+ch*25+j]=v;
        sum+=v; sq=fmaf(v,v,sq); mn=fminf(mn,v); mx=fmaxf(mx,v);
      }
    }
    #pragma unroll
    for (int d=1;d<16;d<<=1){
      sum+=__shfl_xor(sum,d);
      sq +=__shfl_xor(sq,d);
      mn=fminf(mn,__shfl_xor(mn,d));
      mx=fmaxf(mx,__shfl_xor(mx,d));
    }
    if (g==0){
      float* p=wsw+OFF_ST2+((size_t)ch*NBC+blk)*4;
      p[0]=sum; p[1]=sq; p[2]=mn; p[3]=mx;
    }
  }
}

// ---------------- KE: bn2/relu/quant -> fc1 via MFMA -> relu; 256 blocks x 512 thr, 16 img, all 128 cols ----------------
__global__ __launch_bounds__(512) void ke_kernel(InPtrs in, const float* __restrict__ wsr, float* __restrict__ wsw){
  const int t=threadIdx.x, blk=blockIdx.x;
  __shared__ __align__(16) unsigned short xs[16*808];   // [img16][k_eff 800 + 8 pad] bf16 q codes (duplicated)
  __shared__ float sm[16], sisd[16];
  __shared__ float rwn[8], rwx[8];
  const unsigned* U=(const unsigned*)(wsr+OFF_GMM);
  const float lvf=(float)((1<<in.qb[0])-1);
  const float rmn=fdec(U[4]);
  const float rmx=fdec(U[5]);
  if (t<16){ sm[t]=wsr[OFF_BN2+t*4]; sisd[t]=1.0f/wsr[OFF_BN2+t*4+1]; }
  const float s3=(fmaxf(rmx,0.f)-fmaxf(rmn,0.f))/lvf;
  const float inv_s3=1.0f/s3;
  const float inv_s3w=1.0f/wsr[OFF_WSC+2];
  const int b0=blk*16;
  __syncthreads();
  // quantize 16 imgs x 400 k into LDS ONCE
  {
    const int img=t>>5, tg=t&31;
    const float* yrow=wsr+OFF_Y2P+(size_t)(b0+img)*400;
    unsigned* xsu=(unsigned*)xs;
    for (int n=0;n<13;++n){
      int k=n*32+tg;
      if (k<400){
        int ch=(k*5243)>>17;                          // k/25, exact for k<400
        float y=yrow[k];
        float r=fmaxf((y-sm[ch])*sisd[ch],0.f);
        float q=fminf(rintf(r*inv_s3),lvf);
        unsigned qb=__float_as_uint(q)>>16;           // exact: q is an integer <= 255
        xsu[img*404+k]=qb|(qb<<16);
      }
    }
  }
  __syncthreads();
  const int w=t>>6, lane=t&63, l15=lane&15, quad=lane>>4;
  const int ct=w;                                   // output col tile (16 cols), 8 waves cover 128
  const bf16x8* Wf=(const bf16x8*)(wsr+OFF_W3);
  const unsigned short* arow=xs+l15*808;
  f32x4 acc=(f32x4){0.f,0.f,0.f,0.f};
  #pragma unroll 5
  for (int kt=0;kt<25;++kt){
    bf16x8 a=*(const bf16x8*)(arow+kt*32+quad*8);
    bf16x8 b=Wf[(kt*8+ct)*64+lane];
    acc=__builtin_amdgcn_mfma_f32_16x16x32_bf16(a,b,acc,0,0,0);
  }
  const float scale=s3*inv_s3w;
  float hmn=3.4e38f,hmx=-3.4e38f;
  #pragma unroll
  for (int r=0;r<4;++r){
    float h=fmaxf(acc[r]*scale,0.f);
    wsw[OFF_H3+(size_t)(b0+quad*4+r)*128+ct*16+l15]=h;
    hmn=fminf(hmn,h); hmx=fmaxf(hmx,h);
  }
  #pragma unroll
  for (int d=1;d<64;d<<=1){
    hmn=fminf(hmn,__shfl_xor(hmn,d));
    hmx=fmaxf(hmx,__shfl_xor(hmx,d));
  }
  if (lane==0){ rwn[w]=hmn; rwx[w]=hmx; }
  __syncthreads();
  if (t==0){
    float mn=rwn[0], mx=rwx[0];
    #pragma unroll
    for (int i=1;i<8;++i){ mn=fminf(mn,rwn[i]); mx=fmaxf(mx,rwx[i]); }
    float* p=wsw+OFF_MMA+(size_t)blk*2;
    p[0]=mn; p[1]=mx;
  }
}

// ---------------- KF: reduce fc1 min/max partials -> quant -> fc2 -> log_softmax ----------------
__global__ __launch_bounds__(256) void kf_kernel(InPtrs in, const float* __restrict__ wsr, float* __restrict__ out){
  const int t=threadIdx.x, blk=blockIdx.x;
  __shared__ float w4s[1280];
  __shared__ float redn[256], redxs[256];
  const float lvf=(float)((1<<in.qb[0])-1);
  for (int i=t;i<1280;i+=256) w4s[i]=wsr[OFF_W4+i];
  // reduce the 256 per-block fc1 min/max partials (replaces global atomics in ke)
  {
    const float* mmp=wsr+OFF_MMA;
    float mn=3.4e38f, mx=-3.4e38f;
    if (t<NBE){
      mn=mmp[2*t];
      mx=mmp[2*t+1];
    }
    redn[t]=mn; redxs[t]=mx;
    __syncthreads();
    for (int s=128;s>0;s>>=1){
      if (t<s){ redn[t]=fminf(redn[t],redn[t+s]); redxs[t]=fmaxf(redxs[t],redxs[t+s]); }
      __syncthreads();
    }
  }
  const float hmn=redn[0];
  const float hmx=redxs[0];
  const float s4=(hmx-hmn)/lvf;
  const float inv_s4=1.0f/s4;
  const float inv_s4w=1.0f/wsr[OFF_WSC+3];
  const int row=blk*64+(t>>2), l4=t&3;
  const float4* hr4=(const float4*)(wsr+OFF_H3+(size_t)row*128);
  float acc[10];
  #pragma unroll
  for (int j=0;j<10;++j) acc[j]=0.f;
  #pragma unroll 2
  for (int j=0;j<8;++j){
    float4 v=hr4[l4*8+j];
    int kb=(l4*8+j)*4;
    float q0=fminf(rintf(v.x*inv_s4),lvf)*s4;
    float q1=fminf(rintf(v.y*inv_s4),lvf)*s4;
    float q2=fminf(rintf(v.z*inv_s4),lvf)*s4;
    float q3=fminf(rintf(v.w*inv_s4),lvf)*s4;
    #pragma unroll
    for (int o=0;o<10;++o){
      const float* wr=w4s+o*128+kb;
      acc[o]=fmaf(q0,wr[0],acc[o]);
      acc[o]=fmaf(q1,wr[1],acc[o]);
      acc[o]=fmaf(q2,wr[2],acc[o]);
      acc[o]=fmaf(q3,wr[3],acc[o]);
    }
  }
  #pragma unroll
  for (int o=0;o<10;++o){
    acc[o]+=__shfl_xor(acc[o],1);
    acc[o]+=__shfl_xor(acc[o],2);
  }
  if (l4==0){
    float mx=-3.4e38f;
    #pragma unroll
    for (int o=0;o<10;++o){ acc[o]*=inv_s4w; mx=fmaxf(mx,acc[o]); }
    float se=0.f;
    #pragma unroll
    for (int o=0;o<10;++o) se+=expf(acc[o]-mx);
    const float ls=logf(se);
    #pragma unroll
    for (int o=0;o<10;++o) out[row*10+o]=acc[o]-mx-ls;
  }
}

extern "C" void kernel_launch(void* const* d_in, const int* in_sizes, int n_in,
                              void* d_out, int out_size, void* d_ws, size_t ws_size,
                              hipStream_t stream){
  (void)in_sizes; (void)n_in; (void)out_size; (void)ws_size;
  InPtrs P;
  P.x=(const float*)d_in[0];
  for (int l=0;l<4;++l){
    P.sc[l]=(const float*)d_in[1+l*4];
    P.sg[l]=(const float*)d_in[2+l*4];
    P.on[l]=(const float*)d_in[3+l*4];
    P.ze[l]=(const float*)d_in[4+l*4];
  }
  P.qb=(const int*)d_in[17];
  float* ws=(float*)d_ws;

  hipLaunchKernelGGL(ka_kernel,   dim3(NBA+NBW), dim3(256), 0, stream, P, ws);
  hipLaunchKernelGGL(kwp2_kernel, dim3(NBW),     dim3(256), 0, stream, P, ws);
  hipLaunchKernelGGL(kwp3_kernel, dim3(NBW),     dim3(256), 0, stream, P, ws);
  hipLaunchKernelGGL(kw3_kernel,  dim3(NBW),     dim3(256), 0, stream, P, ws);
  hipLaunchKernelGGL(kb_kernel,   dim3(NBB),     dim3(256), 0, stream, P, ws, ws);
  hipLaunchKernelGGL(kstat_kernel, dim3(64), dim3(256), 0, stream, ws, ws,
                     (unsigned long long)OFF_ST1, NBB, 4096.f*144.f, (unsigned long long)OFF_BN1, 2);
  hipLaunchKernelGGL(kc_kernel,   dim3(NBC),     dim3(256), 0, stream, P, ws, ws);
  hipLaunchKernelGGL(kstat_kernel, dim3(16), dim3(256), 0, stream, ws, ws,
                     (unsigned long long)OFF_ST2, NBC, 4096.f*25.f, (unsigned long long)OFF_BN2, 4);
  hipLaunchKernelGGL(ke_kernel,   dim3(NBE),     dim3(512), 0, stream, P, ws, ws);
  hipLaunchKernelGGL(kf_kernel,   dim3(64),      dim3(256), 0, stream, P, ws, (float*)d_out);
}